// Round 9
// baseline (132.074 us; speedup 1.0000x reference)
//
#include <hip/hip_runtime.h>
#include <stdint.h>

#define HID 1024
#define HEADS 16
#define DK 64
#define BB 4
#define TT 2048
#define M_ROWS (BB * TT)  // 8192

typedef __attribute__((ext_vector_type(8))) short s16x8;
typedef __attribute__((ext_vector_type(4))) float f32x4;

__device__ __forceinline__ unsigned short f2bf(float f) {
  unsigned u = __float_as_uint(f);
  u += 0x7fffu + ((u >> 16) & 1u);  // RNE
  return (unsigned short)(u >> 16);
}

__device__ __forceinline__ s16x8 cvt8(float4 a, float4 b) {
  s16x8 v;
  v[0] = (short)f2bf(a.x); v[1] = (short)f2bf(a.y); v[2] = (short)f2bf(a.z); v[3] = (short)f2bf(a.w);
  v[4] = (short)f2bf(b.x); v[5] = (short)f2bf(b.y); v[6] = (short)f2bf(b.z); v[7] = (short)f2bf(b.w);
  return v;
}

__device__ __forceinline__ void gload16(const void* g, void* l) {
  __builtin_amdgcn_global_load_lds(
      (const __attribute__((address_space(1))) unsigned int*)g,
      (__attribute__((address_space(3))) unsigned int*)l, 16, 0, 0);
}

// ------- weight prep: z=0 transpose Wv [in][out] -> bf16 [out][in]; z=1 cvt Wo -------
__global__ void prep_weights(const float* __restrict__ Wv, const float* __restrict__ Wo,
                             unsigned short* __restrict__ wvt, unsigned short* __restrict__ wob) {
  int tx = threadIdx.x, ty = threadIdx.y;
  int i0 = blockIdx.y * 32, o0 = blockIdx.x * 32;
  if (blockIdx.z == 1) {
#pragma unroll
    for (int k = 0; k < 4; ++k)
      wob[(size_t)(i0 + ty + 8 * k) * HID + o0 + tx] = f2bf(Wo[(size_t)(i0 + ty + 8 * k) * HID + o0 + tx]);
    return;
  }
  __shared__ float tile[32][33];
#pragma unroll
  for (int k = 0; k < 4; ++k)
    tile[ty + 8 * k][tx] = Wv[(size_t)(i0 + ty + 8 * k) * HID + o0 + tx];
  __syncthreads();
#pragma unroll
  for (int k = 0; k < 4; ++k)
    wvt[(size_t)(o0 + ty + 8 * k) * HID + i0 + tx] = f2bf(tile[tx][ty + 8 * k]);
}

// -------- A-direct bf16 GEMM: C[M,N] = A[M,K] * Bt[N,K]^T --------
// BM=256, BN=128, BK=64, 512 thr (8 waves 4M x 2N), per-wave 64x64 (acc 4x4).
// A-frags are direct per-lane global loads (L2-hot, x2 panel redundancy),
// double-buffered in registers one K-tile ahead — A is OFF the LDS/barrier path.
// B staged to LDS ring-2 (32 KB total) via gload_lds with T2 slot-XOR swizzle.
// One __syncthreads per K-tile; drained loads were issued a full tile earlier.
// MODE 0: A = fp32 x (in-reg cvt at use); out bf16 scattered to the reference's
//         no-head-transpose ctx layout (einsum collapse: ctx[b,h,t,d]=v[b,t,h,d]).
// MODE 1: A = bf16; out fp32 row-major [M,N].
template <int MODE>
__global__ __launch_bounds__(512, 2) void gemm_adirect(const void* __restrict__ Av,
                                                       const unsigned short* __restrict__ Bt,
                                                       void* __restrict__ outBase) {
  constexpr int Kd = 1024;
  constexpr int NT = 16;
  const int tid = threadIdx.x;
  const int lane = tid & 63;
  const int w = tid >> 6;
  const int wm = w >> 1;  // 0..3 (M)
  const int wn = w & 1;   // 0..1 (N)
  const int lr = lane & 15, lg = lane >> 4;
  // XCD-aware bijective swizzle: 256 blocks = 8 XCDs x 32-chunk; consecutive
  // wids share the A-panel (n-minor) for L2 locality.
  const int lin = blockIdx.x;
  const int wid = (lin & 7) * 32 + (lin >> 3);
  const int blockM = (wid >> 3) * 256;
  const int blockN = (wid & 7) * 128;

  __shared__ __align__(16) short Bbuf[2][128 * 64];  // 32 KB total

  f32x4 acc[4][4] = {};
  const float* Af = (const float*)Av;
  const unsigned short* Ab16 = (const unsigned short*)Av;
  const unsigned short* pb = Bt + (size_t)blockN * Kd;

  // B staging: 2 granule passes; LDS linear (row, slot) <- global (row, slot^(row&7))
  const int srow = tid >> 3;  // 0..63
  const int slot = tid & 7;
  const int sx = (slot ^ (srow & 7)) * 8;
  auto stageB = [&](int bi, int kt) {
    gload16(pb + (size_t)srow * Kd + kt * 64 + sx, (char*)Bbuf[bi] + (size_t)(w * 64) * 16);
    gload16(pb + (size_t)(64 + srow) * Kd + kt * 64 + sx,
            (char*)Bbuf[bi] + (size_t)(512 + w * 64) * 16);
  };

  // A row bases for this thread's 4 fragment rows
  const int arow0 = blockM + wm * 64 + lr;
  // prefetch one K-tile of A-frags into registers (named sets, rule #20)
  float4 a0raw[16], a1raw[16];
  s16x8 a0b[8], a1b[8];
  auto prefA32 = [&](float4* dst, int kt) {
#pragma unroll
    for (int mi = 0; mi < 4; ++mi)
#pragma unroll
      for (int h = 0; h < 2; ++h) {
        const float* p = Af + (size_t)(arow0 + mi * 16) * Kd + kt * 64 + h * 32 + lg * 8;
        dst[(mi * 2 + h) * 2 + 0] = *(const float4*)p;
        dst[(mi * 2 + h) * 2 + 1] = *(const float4*)(p + 4);
      }
  };
  auto prefA16 = [&](s16x8* dst, int kt) {
#pragma unroll
    for (int mi = 0; mi < 4; ++mi)
#pragma unroll
      for (int h = 0; h < 2; ++h)
        dst[mi * 2 + h] = *(const s16x8*)(Ab16 + (size_t)(arow0 + mi * 16) * Kd + kt * 64 + h * 32 + lg * 8);
  };

  // thread-constant swizzled k-half column slots for B frag reads
  const int c0 = (lg ^ (lr & 7)) * 8;
  const int c1 = ((4 + lg) ^ (lr & 7)) * 8;

  auto compute = [&](const float4* raw, const s16x8* a16, const short* Bb) {
#pragma unroll
    for (int h = 0; h < 2; ++h) {
      const int coff = h ? c1 : c0;
      s16x8 af[4], bf[4];
#pragma unroll
      for (int mi = 0; mi < 4; ++mi) {
        if constexpr (MODE == 0)
          af[mi] = cvt8(raw[(mi * 2 + h) * 2], raw[(mi * 2 + h) * 2 + 1]);
        else
          af[mi] = a16[mi * 2 + h];
      }
#pragma unroll
      for (int ni = 0; ni < 4; ++ni)
        bf[ni] = *(const s16x8*)(Bb + (wn * 64 + ni * 16 + lr) * 64 + coff);
      __builtin_amdgcn_s_setprio(1);
#pragma unroll
      for (int mi = 0; mi < 4; ++mi)
#pragma unroll
        for (int ni = 0; ni < 4; ++ni)
          acc[mi][ni] = __builtin_amdgcn_mfma_f32_16x16x32_bf16(af[mi], bf[ni], acc[mi][ni], 0, 0, 0);
      __builtin_amdgcn_s_setprio(0);
    }
  };

  // prologue: A(0) + B(0)
  if constexpr (MODE == 0) prefA32(a0raw, 0); else prefA16(a0b, 0);
  stageB(0, 0);
  __syncthreads();

  for (int t = 0; t < NT; t += 2) {
    stageB(1, t + 1);
    if constexpr (MODE == 0) prefA32(a1raw, t + 1); else prefA16(a1b, t + 1);
    compute(a0raw, a0b, Bbuf[0]);
    __syncthreads();
    if (t + 2 < NT) {
      stageB(0, t + 2);
      if constexpr (MODE == 0) prefA32(a0raw, t + 2); else prefA16(a0b, t + 2);
    }
    compute(a1raw, a1b, Bbuf[1]);
    __syncthreads();
  }

  if constexpr (MODE == 0) {
    unsigned short* out = (unsigned short*)outBase;
#pragma unroll
    for (int mi = 0; mi < 4; ++mi) {
#pragma unroll
      for (int ni = 0; ni < 4; ++ni) {
        int n = blockN + wn * 64 + ni * 16 + lr;
        int h = n >> 6, d = n & 63;
#pragma unroll
        for (int j = 0; j < 4; ++j) {
          int m = blockM + wm * 64 + mi * 16 + lg * 4 + j;
          int b = m >> 11, t = m & 2047;
          size_t row = (size_t)b * TT + h * 128 + (t >> 4);
          out[row * HID + (t & 15) * 64 + d] = f2bf(acc[mi][ni][j]);
        }
      }
    }
  } else {
    float* out = (float*)outBase;
#pragma unroll
    for (int mi = 0; mi < 4; ++mi) {
#pragma unroll
      for (int ni = 0; ni < 4; ++ni) {
        int n = blockN + wn * 64 + ni * 16 + lr;
#pragma unroll
        for (int j = 0; j < 4; ++j) {
          int m = blockM + wm * 64 + mi * 16 + lg * 4 + j;
          out[(size_t)m * HID + n] = acc[mi][ni][j];
        }
      }
    }
  }
}

extern "C" void kernel_launch(void* const* d_in, const int* in_sizes, int n_in,
                              void* d_out, int out_size, void* d_ws, size_t ws_size,
                              hipStream_t stream) {
  const float* x = (const float*)d_in[0];
  // d_in[1] = mask: irrelevant — additive finite mask cannot change sum_l softmax = 1,
  // and the reference's einsum 'bhtl,bthd->bhtd' contracts l over A alone.
  // d_in[2] = Wq, d_in[3] = Wk: unused for the same reason.
  const float* Wv = (const float*)d_in[4];
  const float* Wo = (const float*)d_in[5];

  char* ws = (char*)d_ws;
  unsigned short* Mb  = (unsigned short*)(ws);                 // [0,16M): permuted ctx bf16
  unsigned short* wvt = (unsigned short*)(ws + (16u << 20));   // [16,18M): Wv^T bf16 [out][in]
  unsigned short* wob = (unsigned short*)(ws + (18u << 20));   // [18,20M): Wo bf16 ([out][in] already)

  prep_weights<<<dim3(32, 32, 2), dim3(32, 8), 0, stream>>>(Wv, Wo, wvt, wob);
  gemm_adirect<0><<<256, 512, 0, stream>>>(x, wvt, Mb);
  gemm_adirect<1><<<256, 512, 0, stream>>>(Mb, wob, d_out);
}

// Round 10
// 67.671 us; speedup vs baseline: 1.9517x; 1.9517x over previous
//
#include <hip/hip_runtime.h>
#include <stdint.h>

#define HID 1024
#define HEADS 16
#define DK 64
#define BB 4
#define TT 2048
#define M_ROWS (BB * TT)  // 8192

typedef __attribute__((ext_vector_type(8))) short s16x8;
typedef __attribute__((ext_vector_type(4))) short s16x4;
typedef __attribute__((ext_vector_type(4))) float f32x4;

__device__ __forceinline__ unsigned short f2bf(float f) {
  unsigned u = __float_as_uint(f);
  u += 0x7fffu + ((u >> 16) & 1u);  // RNE
  return (unsigned short)(u >> 16);
}

__device__ __forceinline__ void gload16(const void* g, void* l) {
  __builtin_amdgcn_global_load_lds(
      (const __attribute__((address_space(1))) unsigned int*)g,
      (__attribute__((address_space(3))) unsigned int*)l, 16, 0, 0);
}

// ------- weight prep: z=0 transpose Wv [in][out] -> bf16 [out][in]; z=1 cvt Wo -------
__global__ void prep_weights(const float* __restrict__ Wv, const float* __restrict__ Wo,
                             unsigned short* __restrict__ wvt, unsigned short* __restrict__ wob) {
  int tx = threadIdx.x, ty = threadIdx.y;
  int i0 = blockIdx.y * 32, o0 = blockIdx.x * 32;
  if (blockIdx.z == 1) {
#pragma unroll
    for (int k = 0; k < 4; ++k)
      wob[(size_t)(i0 + ty + 8 * k) * HID + o0 + tx] = f2bf(Wo[(size_t)(i0 + ty + 8 * k) * HID + o0 + tx]);
    return;
  }
  __shared__ float tile[32][33];
#pragma unroll
  for (int k = 0; k < 4; ++k)
    tile[ty + 8 * k][tx] = Wv[(size_t)(i0 + ty + 8 * k) * HID + o0 + tx];
  __syncthreads();
#pragma unroll
  for (int k = 0; k < 4; ++k)
    wvt[(size_t)(o0 + ty + 8 * k) * HID + i0 + tx] = f2bf(tile[tx][ty + 8 * k]);
}

// -------- pack x (fp32 [8192][1024]) -> bf16 MFMA-frag-major A1[m>>4][k>>5][lane][8] --------
// Frag semantics (16x16x32 A-operand): lane l holds A[row = l&15][k = (l>>4)*8 + e].
// A wave's frag load in the GEMM becomes one contiguous 1KB global_load_dwordx4.
__global__ __launch_bounds__(256) void pack_x(const float* __restrict__ x,
                                              unsigned short* __restrict__ A1) {
  constexpr int PAD = 1048;  // shorts; 2096B row stride: 16B-aligned, bank-offset 12/row (2-way max)
  __shared__ unsigned short L[16 * PAD];
  const int mt = blockIdx.x;  // 0..511
  const int t = threadIdx.x;
#pragma unroll
  for (int it = 0; it < 16; ++it) {
    int idx = it * 256 + t;  // float4 index over 16x1024
    int row = idx >> 8, c4 = idx & 255;
    float4 v = *(const float4*)(x + ((size_t)mt * 16 + row) * HID + c4 * 4);
    s16x4 o;
    o[0] = (short)f2bf(v.x); o[1] = (short)f2bf(v.y); o[2] = (short)f2bf(v.z); o[3] = (short)f2bf(v.w);
    *(s16x4*)(&L[row * PAD + c4 * 4]) = o;
  }
  __syncthreads();
#pragma unroll
  for (int it = 0; it < 8; ++it) {
    int wdx = it * 256 + t;  // frag-word index: 32 kc x 64 lanes
    int kc = wdx >> 6, ln = wdx & 63;
    s16x8 o = *(const s16x8*)(&L[(ln & 15) * PAD + kc * 32 + (ln >> 4) * 8]);
    *(s16x8*)(A1 + (((size_t)mt * 32 + kc) * 64 + ln) * 8) = o;
  }
}

// -------- A-frag-stream bf16 GEMM: C[M,N] = A[M,K] * Bt[N,K]^T --------
// BM=256, BN=128, BK=64, 512 thr (8 waves 4M x 2N), per-wave 64x64 (acc 4x4).
// A: frag-major global, coalesced 1KB dwordx4 per frag, double-buffered regs one
//    K-tile ahead, waits via compiler-counted vmcnt — NEVER drained (raw s_barrier,
//    manual vmcnt(8) excludes the 8 in-flight A loads).
// B: LDS ring-2 (32 KB only) via gload_lds, T2 slot-XOR swizzle, barrier-guarded.
// Grid 256 = 1 block/CU; XCD map groups all 8 N-tiles of an M-supertile on one
// XCD so A-frag x8 reuse is XCD-local-L2.
// MODE 0: out -> ctx in frag-major layout for GEMM2 (einsum-collapse permute folded).
// MODE 1: out fp32 row-major [M,N] (d_out).
template <int MODE>
__global__ __launch_bounds__(512, 2) void gemm_fragA(const unsigned short* __restrict__ Afrag,
                                                     const unsigned short* __restrict__ Bt,
                                                     void* __restrict__ outBase) {
  constexpr int Kd = 1024;
  constexpr int NT = 16;
  const int tid = threadIdx.x;
  const int lane = tid & 63;
  const int w = tid >> 6;
  const int wm = w >> 1;  // 0..3
  const int wn = w & 1;   // 0..1
  const int lr = lane & 15, lg = lane >> 4;
  // XCD map: xcd = lin&7 gets M-supertiles [xcd*4, xcd*4+4) x all 8 N-tiles
  const int lin = blockIdx.x;
  const int j = lin >> 3;
  const int mtile = (lin & 7) * 4 + (j >> 3);  // 0..31 (256-row supertiles)
  const int ntile = j & 7;                     // 0..7
  const int blockM = mtile * 256;
  const int blockN = ntile * 128;

  __shared__ __align__(16) short Bbuf[2][128 * 64];  // 32 KB total

  f32x4 acc[4][4] = {};
  const unsigned short* pb = Bt + (size_t)blockN * Kd;

  // B staging: LDS linear (row, slot) <- global (row, slot^(row&7))
  const int srow = tid >> 3;  // 0..63
  const int slot = tid & 7;
  const int sx = (slot ^ (srow & 7)) * 8;
  auto stageB = [&](int bi, int kt) {
    gload16(pb + (size_t)srow * Kd + kt * 64 + sx, (char*)Bbuf[bi] + (size_t)(w * 64) * 16);
    gload16(pb + (size_t)(64 + srow) * Kd + kt * 64 + sx,
            (char*)Bbuf[bi] + (size_t)(512 + w * 64) * 16);
  };

  // A frags: frag (mi,h) of K-tile t lives at ((mt*32 + t*2+h)*64 + lane)*8,
  // mt = mtile*16 + wm*4 + mi  -> per-wave contiguous 1KB loads.
  const unsigned short* paw = Afrag + ((size_t)(mtile * 16 + wm * 4) * 32 * 64 + lane) * 8;
  auto loadA = [&](s16x8* dst, int t) {
#pragma unroll
    for (int mi = 0; mi < 4; ++mi)
#pragma unroll
      for (int h = 0; h < 2; ++h)
        dst[mi * 2 + h] = *(const s16x8*)(paw + ((size_t)mi * 32 + t * 2 + h) * 64 * 8);
  };

  // thread-constant swizzled k-half column slots for B frag reads
  const int c0 = (lg ^ (lr & 7)) * 8;
  const int c1 = ((4 + lg) ^ (lr & 7)) * 8;

  auto compute = [&](const s16x8* a, const short* Bb) {
#pragma unroll
    for (int h = 0; h < 2; ++h) {
      const int coff = h ? c1 : c0;
      s16x8 bf[4];
#pragma unroll
      for (int ni = 0; ni < 4; ++ni)
        bf[ni] = *(const s16x8*)(Bb + (wn * 64 + ni * 16 + lr) * 64 + coff);
      __builtin_amdgcn_s_setprio(1);
#pragma unroll
      for (int mi = 0; mi < 4; ++mi)
#pragma unroll
        for (int ni = 0; ni < 4; ++ni)
          acc[mi][ni] = __builtin_amdgcn_mfma_f32_16x16x32_bf16(a[mi * 2 + h], bf[ni], acc[mi][ni], 0, 0, 0);
      __builtin_amdgcn_s_setprio(0);
    }
  };

  s16x8 a0[8], a1[8];
  // prologue: B(0) + A(0), full drain once.
  stageB(0, 0);
  loadA(a0, 0);
  asm volatile("s_waitcnt vmcnt(0)" ::: "memory");
  __builtin_amdgcn_s_barrier();

  for (int t = 0; t < NT; t += 2) {
    // first half: tile t from a0/Bbuf[0]; prefetch t+1 (B first, then 8 A loads)
    stageB(1, t + 1);
    loadA(a1, t + 1);
    compute(a0, Bbuf[0]);
    asm volatile("s_waitcnt vmcnt(8)" ::: "memory");  // B(t+1) landed; A(t+1) stays in flight
    __builtin_amdgcn_s_barrier();
    // second half: tile t+1 from a1/Bbuf[1]; prefetch t+2
    if (t + 2 < NT) {
      stageB(0, t + 2);
      loadA(a0, t + 2);
    }
    compute(a1, Bbuf[1]);
    if (t + 2 < NT) {
      asm volatile("s_waitcnt vmcnt(8)" ::: "memory");
      __builtin_amdgcn_s_barrier();
    }
  }

  if constexpr (MODE == 0) {
    // write ctx (einsum collapse: ctx[b,h,t,d] = v[b,t,h,d]) directly in
    // frag-major layout for GEMM2: A2[R>>4][C>>5][lane2][C&7]
    unsigned short* out = (unsigned short*)outBase;
#pragma unroll
    for (int mi = 0; mi < 4; ++mi) {
#pragma unroll
      for (int ni = 0; ni < 4; ++ni) {
        int n = blockN + wn * 64 + ni * 16 + lr;
        int hh = n >> 6, d = n & 63;
#pragma unroll
        for (int jj = 0; jj < 4; ++jj) {
          int m = blockM + wm * 64 + mi * 16 + lg * 4 + jj;
          int b = m >> 11, tq = m & 2047;
          int R = b * 2048 + hh * 128 + (tq >> 4);
          int C = (tq & 15) * 64 + d;
          int mt = R >> 4, kc = C >> 5;
          int lane2 = (R & 15) | (((C >> 3) & 3) << 4);
          out[(((size_t)mt * 32 + kc) * 64 + lane2) * 8 + (C & 7)] = f2bf(acc[mi][ni][jj]);
        }
      }
    }
  } else {
    float* out = (float*)outBase;
#pragma unroll
    for (int mi = 0; mi < 4; ++mi) {
#pragma unroll
      for (int ni = 0; ni < 4; ++ni) {
        int n = blockN + wn * 64 + ni * 16 + lr;
#pragma unroll
        for (int jj = 0; jj < 4; ++jj) {
          int m = blockM + wm * 64 + mi * 16 + lg * 4 + jj;
          out[(size_t)m * HID + n] = acc[mi][ni][jj];
        }
      }
    }
  }
}

extern "C" void kernel_launch(void* const* d_in, const int* in_sizes, int n_in,
                              void* d_out, int out_size, void* d_ws, size_t ws_size,
                              hipStream_t stream) {
  const float* x = (const float*)d_in[0];
  // d_in[1] = mask: irrelevant — additive finite mask cannot change sum_l softmax = 1,
  // and the reference's einsum 'bhtl,bthd->bhtd' contracts l over A alone.
  // d_in[2] = Wq, d_in[3] = Wk: unused for the same reason.
  const float* Wv = (const float*)d_in[4];
  const float* Wo = (const float*)d_in[5];

  char* ws = (char*)d_ws;
  unsigned short* A1x  = (unsigned short*)(ws);                // [0,16M): x bf16 frag-major
  unsigned short* ctxf = (unsigned short*)(ws + (16u << 20));  // [16,32M): ctx bf16 frag-major
  unsigned short* wvt  = (unsigned short*)(ws + (32u << 20));  // [32,34M): Wv^T bf16 [out][in]
  unsigned short* wob  = (unsigned short*)(ws + (34u << 20));  // [34,36M): Wo bf16 ([out][in] already)

  prep_weights<<<dim3(32, 32, 2), dim3(32, 8), 0, stream>>>(Wv, Wo, wvt, wob);
  pack_x<<<512, 256, 0, stream>>>(x, A1x);
  gemm_fragA<0><<<256, 512, 0, stream>>>(A1x, wvt, ctxf);
  gemm_fragA<1><<<256, 512, 0, stream>>>(ctxf, wob, d_out);
}

// Round 12
// 62.985 us; speedup vs baseline: 2.0969x; 1.0744x over previous
//
#include <hip/hip_runtime.h>
#include <stdint.h>

#define HID 1024
#define BB 4
#define TT 2048
#define M_ROWS (BB * TT)  // 8192

typedef __attribute__((ext_vector_type(8))) short s16x8;
typedef __attribute__((ext_vector_type(4))) float f32x4;

__device__ __forceinline__ unsigned short f2bf(float f) {
  unsigned u = __float_as_uint(f);
  u += 0x7fffu + ((u >> 16) & 1u);  // RNE
  return (unsigned short)(u >> 16);
}

__device__ __forceinline__ s16x8 cvt8(float4 a, float4 b) {
  s16x8 v;
  v[0] = (short)f2bf(a.x); v[1] = (short)f2bf(a.y); v[2] = (short)f2bf(a.z); v[3] = (short)f2bf(a.w);
  v[4] = (short)f2bf(b.x); v[5] = (short)f2bf(b.y); v[6] = (short)f2bf(b.z); v[7] = (short)f2bf(b.w);
  return v;
}

// -------- pack weights to MFMA-frag-major bf16: F[n>>4][k>>5][lane][8] --------
// frag lane l holds F[n16*16 + (l&15)][kc*32 + (l>>4)*8 + e].
// z=0: F(n,k) = Wv[k][n] (transpose); z=1: F(n,k) = Wo[n][k].
__global__ void pack_w(const float* __restrict__ Wv, const float* __restrict__ Wo,
                       unsigned short* __restrict__ wvf, unsigned short* __restrict__ wof) {
  const int tx = threadIdx.x, ty = threadIdx.y;  // 32x8
  const int n0 = blockIdx.x * 32, k0 = blockIdx.y * 32;
  __shared__ float tileF[32][33];
  if (blockIdx.z == 0) {
#pragma unroll
    for (int kk = 0; kk < 4; ++kk)
      tileF[tx][ty + 8 * kk] = Wv[(size_t)(k0 + ty + 8 * kk) * HID + n0 + tx];
  } else {
#pragma unroll
    for (int kk = 0; kk < 4; ++kk)
      tileF[ty + 8 * kk][tx] = Wo[(size_t)(n0 + ty + 8 * kk) * HID + k0 + tx];
  }
  __syncthreads();
  unsigned short* out = (blockIdx.z == 0) ? wvf : wof;
  int j = ty * 32 + tx;
  if (j < 128) {
    int n16h = j >> 6, lane = j & 63;
    int nn = n16h * 16 + (lane & 15);
    int kk = (lane >> 4) * 8;
    s16x8 wv;
#pragma unroll
    for (int e = 0; e < 8; ++e) wv[e] = (short)f2bf(tileF[nn][kk + e]);
    size_t idx = (((size_t)(n0 / 16 + n16h) * 32 + (k0 >> 5)) * 64 + lane) * 8;
    *(s16x8*)(out + idx) = wv;
  }
}

// -------- GEMM1: ctx_frag = permute(x @ Wv) --------
// BM=BN=128, BK=64, 256 thr (4 waves 2x2), per-wave 64x64.
// A: x fp32 reg-staged + cvt -> swizzled LDS (ring-2, 32 KB -> many blocks/CU).
// B: Wv^T frag-major, streamed from L2 into registers (no LDS, no barrier cost).
// One __syncthreads per K-tile (guards A only).
// Epilogue: ctx written FRAG-MAJOR (einsum collapse ctx[b,h,t,d]=v[b,t,h,d] folded).
__global__ __launch_bounds__(256, 2) void gemm1(const float* __restrict__ x,
                                                const unsigned short* __restrict__ Bf,
                                                unsigned short* __restrict__ ctxf) {
  constexpr int NT = 16;
  const int tid = threadIdx.x;
  const int lane = tid & 63;
  const int w = tid >> 6;
  const int wm = w >> 1, wn = w & 1;
  const int lr = lane & 15, lg = lane >> 4;
  const int lin = blockIdx.x;
  const int wid = (lin & 7) * 64 + (lin >> 3);  // XCD-bijective
  const int blockM = (wid >> 3) * 128;
  const int blockN = (wid & 7) * 128;

  __shared__ __align__(16) short Abuf[2][128 * 64];  // 32 KB

  f32x4 acc[4][4] = {};

  // A staging (fp32 -> bf16, swizzled LDS write; rule #21 both-sides)
  const int srow8 = tid >> 3;  // 0..31
  const int slot = tid & 7;
  float4 areg[8];
  auto loadA32 = [&](int kt) {
#pragma unroll
    for (int u = 0; u < 4; ++u) {
      const float* s = x + (size_t)(blockM + u * 32 + srow8) * HID + kt * 64 + slot * 8;
      areg[u * 2] = *(const float4*)s;
      areg[u * 2 + 1] = *(const float4*)(s + 4);
    }
  };
  auto writeA32 = [&](int bi) {
#pragma unroll
    for (int u = 0; u < 4; ++u) {
      int row = u * 32 + srow8;
      *(s16x8*)(Abuf[bi] + row * 64 + (slot ^ (row & 7)) * 8) = cvt8(areg[u * 2], areg[u * 2 + 1]);
    }
  };

  // B frag stream: frag (ni,h) of tile t at pbw + (ni*32 + t*2+h)*512
  const unsigned short* pbw = Bf + (size_t)(blockN / 16 + wn * 4) * 16384 + lane * 8;
  auto loadB = [&](s16x8* dst, int t) {
#pragma unroll
    for (int ni = 0; ni < 4; ++ni)
#pragma unroll
      for (int h = 0; h < 2; ++h)
        dst[ni * 2 + h] = *(const s16x8*)(pbw + ((size_t)ni * 32 + t * 2 + h) * 512);
  };

  const int c0 = (lg ^ (lr & 7)) * 8;
  const int c1 = ((4 + lg) ^ (lr & 7)) * 8;
  auto compute = [&](const s16x8* b, const short* Ab) {
#pragma unroll
    for (int h = 0; h < 2; ++h) {
      const int coff = h ? c1 : c0;
      s16x8 af[4];
#pragma unroll
      for (int mi = 0; mi < 4; ++mi)
        af[mi] = *(const s16x8*)(Ab + (wm * 64 + mi * 16 + lr) * 64 + coff);
      __builtin_amdgcn_s_setprio(1);
#pragma unroll
      for (int mi = 0; mi < 4; ++mi)
#pragma unroll
        for (int ni = 0; ni < 4; ++ni)
          acc[mi][ni] = __builtin_amdgcn_mfma_f32_16x16x32_bf16(af[mi], b[ni * 2 + h], acc[mi][ni], 0, 0, 0);
      __builtin_amdgcn_s_setprio(0);
    }
  };

  s16x8 b0[8], b1[8];
  loadA32(0);
  loadB(b0, 0);
  writeA32(0);
  __syncthreads();

  for (int t = 0; t < NT; t += 2) {
    loadA32(t + 1);
    loadB(b1, t + 1);
    compute(b0, Abuf[0]);
    writeA32(1);
    __syncthreads();
    if (t + 2 < NT) {
      loadA32(t + 2);
      loadB(b0, t + 2);
    }
    compute(b1, Abuf[1]);
    if (t + 2 < NT) {
      writeA32(0);
      __syncthreads();
    }
  }

  // ctx frag-major write: A2[R>>4][C>>5][lane2][C&7]
#pragma unroll
  for (int mi = 0; mi < 4; ++mi) {
#pragma unroll
    for (int ni = 0; ni < 4; ++ni) {
      int n = blockN + wn * 64 + ni * 16 + lr;
      int hh = n >> 6, d = n & 63;
#pragma unroll
      for (int jj = 0; jj < 4; ++jj) {
        int m = blockM + wm * 64 + mi * 16 + lg * 4 + jj;
        int b = m >> 11, tq = m & 2047;
        int R = b * 2048 + hh * 128 + (tq >> 4);
        int C = (tq & 15) * 64 + d;
        size_t idx = (((size_t)(R >> 4) * 32 + (C >> 5)) * 64 + ((R & 15) | (((C >> 3) & 3) << 4))) * 8 + (C & 7);
        ctxf[idx] = f2bf(acc[mi][ni][jj]);
      }
    }
  }
}

// -------- GEMM2: out = ctx @ Wo^T, pure streaming (no LDS, no barriers) --------
// BM=BN=128, 256 thr (4 waves 2x2), per-wave 64x64. Both operands frag-major,
// coalesced 1KB dwordx4 loads from L2, double-buffered one K-tile ahead.
__global__ __launch_bounds__(256, 2) void gemm2(const unsigned short* __restrict__ Af,
                                                const unsigned short* __restrict__ Bf,
                                                float* __restrict__ out) {
  constexpr int NT = 16;
  const int tid = threadIdx.x;
  const int lane = tid & 63;
  const int w = tid >> 6;
  const int wm = w >> 1, wn = w & 1;
  const int lr = lane & 15, lg = lane >> 4;
  const int lin = blockIdx.x;
  const int wid = (lin & 7) * 64 + (lin >> 3);  // XCD-bijective
  const int blockM = (wid >> 3) * 128;
  const int blockN = (wid & 7) * 128;

  f32x4 acc[4][4] = {};
  const unsigned short* paw = Af + (size_t)(blockM / 16 + wm * 4) * 16384 + lane * 8;
  const unsigned short* pbw = Bf + (size_t)(blockN / 16 + wn * 4) * 16384 + lane * 8;

  auto loadA = [&](s16x8* dst, int t) {
#pragma unroll
    for (int mi = 0; mi < 4; ++mi)
#pragma unroll
      for (int h = 0; h < 2; ++h)
        dst[mi * 2 + h] = *(const s16x8*)(paw + ((size_t)mi * 32 + t * 2 + h) * 512);
  };
  auto loadB = [&](s16x8* dst, int t) {
#pragma unroll
    for (int ni = 0; ni < 4; ++ni)
#pragma unroll
      for (int h = 0; h < 2; ++h)
        dst[ni * 2 + h] = *(const s16x8*)(pbw + ((size_t)ni * 32 + t * 2 + h) * 512);
  };
  auto compute = [&](const s16x8* a, const s16x8* b) {
#pragma unroll
    for (int h = 0; h < 2; ++h) {
      __builtin_amdgcn_s_setprio(1);
#pragma unroll
      for (int mi = 0; mi < 4; ++mi)
#pragma unroll
        for (int ni = 0; ni < 4; ++ni)
          acc[mi][ni] = __builtin_amdgcn_mfma_f32_16x16x32_bf16(a[mi * 2 + h], b[ni * 2 + h], acc[mi][ni], 0, 0, 0);
      __builtin_amdgcn_s_setprio(0);
    }
  };

  s16x8 a0[8], b0[8], a1[8], b1[8];
  loadA(a0, 0);
  loadB(b0, 0);
  for (int t = 0; t < NT; t += 2) {
    if (t + 1 < NT) { loadA(a1, t + 1); loadB(b1, t + 1); }
    compute(a0, b0);
    if (t + 2 < NT) { loadA(a0, t + 2); loadB(b0, t + 2); }
    compute(a1, b1);
  }

#pragma unroll
  for (int mi = 0; mi < 4; ++mi) {
#pragma unroll
    for (int ni = 0; ni < 4; ++ni) {
      int n = blockN + wn * 64 + ni * 16 + lr;
#pragma unroll
      for (int jj = 0; jj < 4; ++jj) {
        int m = blockM + wm * 64 + mi * 16 + lg * 4 + jj;
        out[(size_t)m * HID + n] = acc[mi][ni][jj];
      }
    }
  }
}

extern "C" void kernel_launch(void* const* d_in, const int* in_sizes, int n_in,
                              void* d_out, int out_size, void* d_ws, size_t ws_size,
                              hipStream_t stream) {
  const float* x = (const float*)d_in[0];
  // d_in[1] = mask: irrelevant — additive finite mask cannot change sum_l softmax = 1,
  // and the reference's einsum 'bhtl,bthd->bhtd' contracts l over A alone.
  // d_in[2] = Wq, d_in[3] = Wk: unused for the same reason.
  const float* Wv = (const float*)d_in[4];
  const float* Wo = (const float*)d_in[5];

  char* ws = (char*)d_ws;
  unsigned short* ctxf = (unsigned short*)(ws);                // [0,16M): ctx bf16 frag-major
  unsigned short* wvf  = (unsigned short*)(ws + (16u << 20));  // [16,18M): Wv^T frag-major bf16
  unsigned short* wof  = (unsigned short*)(ws + (18u << 20));  // [18,20M): Wo frag-major bf16

  pack_w<<<dim3(32, 32, 2), dim3(32, 8), 0, stream>>>(Wv, Wo, wvf, wof);
  gemm1<<<512, 256, 0, stream>>>(x, wvf, ctxf);
  gemm2<<<512, 256, 0, stream>>>(ctxf, wof, (float*)d_out);
}

// Round 14
// 59.089 us; speedup vs baseline: 2.2352x; 1.0659x over previous
//
#include <hip/hip_runtime.h>
#include <stdint.h>

#define HID 1024
#define BB 4
#define TT 2048
#define M_ROWS (BB * TT)  // 8192

typedef __attribute__((ext_vector_type(8))) short s16x8;
typedef __attribute__((ext_vector_type(4))) float f32x4;

__device__ __forceinline__ unsigned short f2bf(float f) {
  unsigned u = __float_as_uint(f);
  u += 0x7fffu + ((u >> 16) & 1u);  // RNE
  return (unsigned short)(u >> 16);
}

__device__ __forceinline__ s16x8 cvt8(float4 a, float4 b) {
  s16x8 v;
  v[0] = (short)f2bf(a.x); v[1] = (short)f2bf(a.y); v[2] = (short)f2bf(a.z); v[3] = (short)f2bf(a.w);
  v[4] = (short)f2bf(b.x); v[5] = (short)f2bf(b.y); v[6] = (short)f2bf(b.z); v[7] = (short)f2bf(b.w);
  return v;
}

__device__ __forceinline__ void gload16(const void* g, void* l) {
  __builtin_amdgcn_global_load_lds(
      (const __attribute__((address_space(1))) unsigned int*)g,
      (__attribute__((address_space(3))) unsigned int*)l, 16, 0, 0);
}

// ------- weight prep: z=0 transpose Wv [in][out] -> bf16 [out][in]; z=1 cvt Wo -------
__global__ void prep_weights(const float* __restrict__ Wv, const float* __restrict__ Wo,
                             unsigned short* __restrict__ wvt, unsigned short* __restrict__ wob) {
  int tx = threadIdx.x, ty = threadIdx.y;
  int i0 = blockIdx.y * 32, o0 = blockIdx.x * 32;
  if (blockIdx.z == 1) {
#pragma unroll
    for (int k = 0; k < 4; ++k)
      wob[(size_t)(i0 + ty + 8 * k) * HID + o0 + tx] = f2bf(Wo[(size_t)(i0 + ty + 8 * k) * HID + o0 + tx]);
    return;
  }
  __shared__ float tile[32][33];
#pragma unroll
  for (int k = 0; k < 4; ++k)
    tile[ty + 8 * k][tx] = Wv[(size_t)(i0 + ty + 8 * k) * HID + o0 + tx];
  __syncthreads();
#pragma unroll
  for (int k = 0; k < 4; ++k)
    wvt[(size_t)(o0 + ty + 8 * k) * HID + i0 + tx] = f2bf(tile[tx][ty + 8 * k]);
}

// ---- GEMM1 (deep pipeline): Mb = permute(x @ Wv^T-packed) ----
// BM=BN=128, BK=64, 512 thr (8 waves 2Mx4N), per-wave 64x32 (acc 4x2).
// A: x fp32, reg-staged TWO tiles ahead (aA/aB named buffers), cvt+swizzled
//    ds_write one tile ahead. B: bf16 gload_lds ring-3 LDS, staged two ahead.
// Per iter: issue(t+2) -> ds_read frags(t) -> 32 MFMA -> vmcnt(6) [counted:
// only the 6 newest (t+2) ops stay in flight; oldest-retire => (t+1) landed]
// -> writeA(t+1) -> lgkmcnt(0) -> raw s_barrier. Never drains the pipeline.
// LDS 80 KB -> 2 blocks/CU (16 waves). T2 slot-XOR swizzle; T1 XCD swizzle.
__global__ __launch_bounds__(512, 4) void gemm1_deep(const float* __restrict__ x,
                                                     const unsigned short* __restrict__ Bt,
                                                     unsigned short* __restrict__ Mb) {
  constexpr int Kd = 1024;
  const int tid = threadIdx.x;
  const int lane = tid & 63;
  const int w = tid >> 6;
  const int wm = w >> 2;  // 0..1
  const int wn = w & 3;   // 0..3
  const int lr = lane & 15, lg = lane >> 4;
  const int lin = blockIdx.x;
  const int wid = (lin & 7) * 64 + (lin >> 3);  // XCD-bijective (512 = 8x64)
  const int blockN = (wid & 7) * 128;
  const int blockM = (wid >> 3) * 128;

  __shared__ __align__(16) short Abuf[2][128 * 64];  // 32 KB
  __shared__ __align__(16) short Bbuf[3][128 * 64];  // 48 KB

  f32x4 acc[4][2] = {};
  const unsigned short* pb = Bt + (size_t)blockN * Kd;

  const int srow = tid >> 3;  // 0..63
  const int slot = tid & 7;
  const int sx = (slot ^ (srow & 7)) * 8;

  auto stageB = [&](int bi, int kt) {
    gload16(pb + (size_t)srow * Kd + kt * 64 + sx, (char*)Bbuf[bi] + (size_t)(w * 64) * 16);
    gload16(pb + (size_t)(64 + srow) * Kd + kt * 64 + sx,
            (char*)Bbuf[bi] + (size_t)(512 + w * 64) * 16);
  };
  auto loadA32 = [&](float4* dst, int kt) {
    const float* s0 = x + (size_t)(blockM + srow) * Kd + kt * 64 + slot * 8;
    dst[0] = *(const float4*)s0;
    dst[1] = *(const float4*)(s0 + 4);
    const float* s1 = x + (size_t)(blockM + 64 + srow) * Kd + kt * 64 + slot * 8;
    dst[2] = *(const float4*)s1;
    dst[3] = *(const float4*)(s1 + 4);
  };
  auto writeA32 = [&](int bi, const float4* src) {
    *(s16x8*)(Abuf[bi] + srow * 64 + (slot ^ (srow & 7)) * 8) = cvt8(src[0], src[1]);
    *(s16x8*)(Abuf[bi] + (64 + srow) * 64 + (slot ^ (srow & 7)) * 8) = cvt8(src[2], src[3]);
  };

  const int c0 = (lg ^ (lr & 7)) * 8;
  const int c1 = ((4 + lg) ^ (lr & 7)) * 8;

  auto compute = [&](const short* Ab, const short* Bb) {
#pragma unroll
    for (int h = 0; h < 2; ++h) {
      const int coff = h ? c1 : c0;
      s16x8 af[4], bf[2];
#pragma unroll
      for (int mi = 0; mi < 4; ++mi)
        af[mi] = *(const s16x8*)(Ab + (wm * 64 + mi * 16 + lr) * 64 + coff);
#pragma unroll
      for (int ni = 0; ni < 2; ++ni)
        bf[ni] = *(const s16x8*)(Bb + (wn * 32 + ni * 16 + lr) * 64 + coff);
      __builtin_amdgcn_s_setprio(1);
#pragma unroll
      for (int mi = 0; mi < 4; ++mi)
#pragma unroll
        for (int ni = 0; ni < 2; ++ni)
          acc[mi][ni] = __builtin_amdgcn_mfma_f32_16x16x32_bf16(af[mi], bf[ni], acc[mi][ni], 0, 0, 0);
      __builtin_amdgcn_s_setprio(0);
    }
  };

  float4 aA[4], aB[4];
  // ---- prologue: tiles 0 (to LDS) and 1 (in regs), counted waits only ----
  loadA32(aA, 0);          // 4 vmem
  stageB(0, 0);            // +2 = 6
  asm volatile("s_waitcnt vmcnt(2)" ::: "memory");  // A(0) regs ready
  writeA32(0, aA);
  loadA32(aA, 1);          // outstanding: B0(2)+A1(4) = 6
  stageB(1, 1);            // +2 = 8
  asm volatile("s_waitcnt vmcnt(6) lgkmcnt(0)" ::: "memory");  // B(0) in LDS, A(0) writes done
  __builtin_amdgcn_s_barrier();

#define G1_ITER(T_, AP_, AQ_)                                          \
  {                                                                    \
    const int t_ = (T_);                                               \
    stageB((t_ + 2) % 3, t_ + 2);                                      \
    loadA32(AQ_, t_ + 2);                                              \
    compute(Abuf[t_ & 1], Bbuf[t_ % 3]);                               \
    asm volatile("s_waitcnt vmcnt(6)" ::: "memory");                   \
    writeA32((t_ + 1) & 1, AP_);                                       \
    asm volatile("s_waitcnt lgkmcnt(0)" ::: "memory");                 \
    __builtin_amdgcn_s_barrier();                                      \
  }

  for (int t = 0; t < 14; t += 2) {
    G1_ITER(t, aA, aB);
    G1_ITER(t + 1, aB, aA);
  }
#undef G1_ITER
  // t = 14: nothing left to issue; drain what remains (B15 -> LDS, A15 regs)
  compute(Abuf[0], Bbuf[14 % 3]);
  asm volatile("s_waitcnt vmcnt(0)" ::: "memory");
  writeA32(1, aA);
  asm volatile("s_waitcnt lgkmcnt(0)" ::: "memory");
  __builtin_amdgcn_s_barrier();
  // t = 15: compute only
  compute(Abuf[1], Bbuf[15 % 3]);

  // epilogue: permuted ctx layout (einsum collapse ctx[b,h,t,d]=v[b,t,h,d])
#pragma unroll
  for (int mi = 0; mi < 4; ++mi) {
#pragma unroll
    for (int ni = 0; ni < 2; ++ni) {
      int n = blockN + wn * 32 + ni * 16 + lr;
      int h = n >> 6, d = n & 63;
#pragma unroll
      for (int j = 0; j < 4; ++j) {
        int m = blockM + wm * 64 + mi * 16 + lg * 4 + j;
        int b = m >> 11, t = m & 2047;
        size_t row = (size_t)b * TT + h * 128 + (t >> 4);
        Mb[row * HID + (t & 15) * 64 + d] = f2bf(acc[mi][ni][j]);
      }
    }
  }
}

// ---- GEMM2 (r8-verbatim): out = Mb @ Wo^T, A+B bf16 gload_lds ring-2 ----
__global__ __launch_bounds__(512, 4) void gemm2k(const unsigned short* __restrict__ Av,
                                                 const unsigned short* __restrict__ Bt,
                                                 float* __restrict__ out) {
  constexpr int Kd = 1024;
  constexpr int NT = 16;
  const int tid = threadIdx.x;
  const int lane = tid & 63;
  const int w = tid >> 6;
  const int wm = w >> 2;
  const int wn = w & 3;
  const int lr = lane & 15, lg = lane >> 4;
  const int lin = blockIdx.x;
  const int wid = (lin & 7) * 64 + (lin >> 3);
  const int blockN = (wid & 7) * 128;
  const int blockM = (wid >> 3) * 128;

  __shared__ __align__(16) short Abuf[2][128 * 64];
  __shared__ __align__(16) short Bbuf[2][128 * 64];

  f32x4 acc[4][2] = {};
  const unsigned short* pb = Bt + (size_t)blockN * Kd;

  const int srow = tid >> 3;
  const int slot = tid & 7;
  const int sx = (slot ^ (srow & 7)) * 8;

  auto stageB = [&](int bi, int kt) {
    gload16(pb + (size_t)srow * Kd + kt * 64 + sx, (char*)Bbuf[bi] + (size_t)(w * 64) * 16);
    gload16(pb + (size_t)(64 + srow) * Kd + kt * 64 + sx,
            (char*)Bbuf[bi] + (size_t)(512 + w * 64) * 16);
  };
  auto stageA = [&](int bi, int kt) {
    gload16(Av + (size_t)(blockM + srow) * Kd + kt * 64 + sx,
            (char*)Abuf[bi] + (size_t)(w * 64) * 16);
    gload16(Av + (size_t)(blockM + 64 + srow) * Kd + kt * 64 + sx,
            (char*)Abuf[bi] + (size_t)(512 + w * 64) * 16);
  };

  const int c0 = (lg ^ (lr & 7)) * 8;
  const int c1 = ((4 + lg) ^ (lr & 7)) * 8;

  stageA(0, 0);
  stageB(0, 0);
  __syncthreads();

  for (int t = 0; t < NT; ++t) {
    const short* Ab = Abuf[t & 1];
    const short* Bb = Bbuf[t & 1];
    const int bn = (t + 1) & 1;
    if (t + 1 < NT) {
      stageA(bn, t + 1);
      stageB(bn, t + 1);
    }
#pragma unroll
    for (int h = 0; h < 2; ++h) {
      const int coff = h ? c1 : c0;
      s16x8 af[4], bf[2];
#pragma unroll
      for (int mi = 0; mi < 4; ++mi)
        af[mi] = *(const s16x8*)(Ab + (wm * 64 + mi * 16 + lr) * 64 + coff);
#pragma unroll
      for (int ni = 0; ni < 2; ++ni)
        bf[ni] = *(const s16x8*)(Bb + (wn * 32 + ni * 16 + lr) * 64 + coff);
      __builtin_amdgcn_s_setprio(1);
#pragma unroll
      for (int mi = 0; mi < 4; ++mi)
#pragma unroll
        for (int ni = 0; ni < 2; ++ni)
          acc[mi][ni] = __builtin_amdgcn_mfma_f32_16x16x32_bf16(af[mi], bf[ni], acc[mi][ni], 0, 0, 0);
      __builtin_amdgcn_s_setprio(0);
    }
    if (t + 1 < NT) __syncthreads();
  }

#pragma unroll
  for (int mi = 0; mi < 4; ++mi) {
#pragma unroll
    for (int ni = 0; ni < 2; ++ni) {
      int n = blockN + wn * 32 + ni * 16 + lr;
#pragma unroll
      for (int j = 0; j < 4; ++j) {
        int m = blockM + wm * 64 + mi * 16 + lg * 4 + j;
        out[(size_t)m * HID + n] = acc[mi][ni][j];
      }
    }
  }
}

extern "C" void kernel_launch(void* const* d_in, const int* in_sizes, int n_in,
                              void* d_out, int out_size, void* d_ws, size_t ws_size,
                              hipStream_t stream) {
  const float* x = (const float*)d_in[0];
  // d_in[1] = mask: irrelevant — additive finite mask cannot change sum_l softmax = 1,
  // and the reference's einsum 'bhtl,bthd->bhtd' contracts l over A alone.
  // d_in[2] = Wq, d_in[3] = Wk: unused for the same reason.
  const float* Wv = (const float*)d_in[4];
  const float* Wo = (const float*)d_in[5];

  char* ws = (char*)d_ws;
  unsigned short* Mb  = (unsigned short*)(ws);                 // [0,16M): permuted ctx bf16
  unsigned short* wvt = (unsigned short*)(ws + (16u << 20));   // [16,18M): Wv^T bf16 [out][in]
  unsigned short* wob = (unsigned short*)(ws + (18u << 20));   // [18,20M): Wo bf16 ([out][in] already)

  prep_weights<<<dim3(32, 32, 2), dim3(32, 8), 0, stream>>>(Wv, Wo, wvt, wob);
  gemm1_deep<<<512, 512, 0, stream>>>(x, wvt, Mb);
  gemm2k<<<512, 512, 0, stream>>>(Mb, wob, (float*)d_out);
}